// Round 3
// baseline (1379.416 us; speedup 1.0000x reference)
//
#include <hip/hip_runtime.h>
#include <cstdint>
#include <cstddef>

#define NNODES 10000
#define DIM 256
#define MNB 32
#define NT 79   // ceil(10000/128)

typedef __attribute__((ext_vector_type(8))) short bf16x8;
typedef __attribute__((ext_vector_type(4))) float f32x4;

// ---------------------------------------------------------------------------
// Kernel 0: split agg (f32) into bf16 hi/lo arrays (RNE both).
// ---------------------------------------------------------------------------
__device__ inline unsigned short bf16_rne(float f) {
    unsigned int u = __float_as_uint(f);
    u = u + 0x7FFFu + ((u >> 16) & 1u);
    return (unsigned short)(u >> 16);
}

__global__ __launch_bounds__(256) void split_kernel(
    const float* __restrict__ agg,
    unsigned short* __restrict__ hi,
    unsigned short* __restrict__ lo)
{
    const int i = blockIdx.x * 256 + threadIdx.x;      // 8 floats per thread
    if (i >= NNODES * DIM / 8) return;
    float4 a = ((const float4*)agg)[i * 2];
    float4 b = ((const float4*)agg)[i * 2 + 1];
    float f[8] = {a.x, a.y, a.z, a.w, b.x, b.y, b.z, b.w};
    unsigned int hp[4], lp[4];
    #pragma unroll
    for (int j = 0; j < 4; ++j) {
        unsigned short h0 = bf16_rne(f[2 * j]);
        unsigned short h1 = bf16_rne(f[2 * j + 1]);
        float hf0 = __uint_as_float((unsigned int)h0 << 16);
        float hf1 = __uint_as_float((unsigned int)h1 << 16);
        unsigned short l0 = bf16_rne(f[2 * j] - hf0);
        unsigned short l1 = bf16_rne(f[2 * j + 1] - hf1);
        hp[j] = (unsigned int)h0 | ((unsigned int)h1 << 16);
        lp[j] = (unsigned int)l0 | ((unsigned int)l1 << 16);
    }
    ((uint4*)hi)[i] = make_uint4(hp[0], hp[1], hp[2], hp[3]);
    ((uint4*)lo)[i] = make_uint4(lp[0], lp[1], lp[2], lp[3]);
}

// ---------------------------------------------------------------------------
// Kernel 1: attention context. One block (256 thr) per node.
// ---------------------------------------------------------------------------
__global__ __launch_bounds__(256) void attn_ctx_kernel(
    const float* __restrict__ agg,
    const int* __restrict__ nb_id,
    float* __restrict__ ctx)
{
    const int n = blockIdx.x;
    const int t = threadIdx.x;
    __shared__ float s_agg[DIM];
    __shared__ float s_score[MNB];
    __shared__ int   s_idx[MNB];

    s_agg[t] = agg[(size_t)n * DIM + t];
    if (t < MNB) s_idx[t] = nb_id[n * MNB + t];
    __syncthreads();

    const int wave = t >> 6;
    const int lane = t & 63;

    #pragma unroll
    for (int mi = 0; mi < 8; ++mi) {
        const int m = wave * 8 + mi;
        const int idx = s_idx[m];
        float p = 0.f;
        if (idx >= 0) {
            const float* row = agg + (size_t)idx * DIM;
            #pragma unroll
            for (int j = 0; j < 4; ++j) {
                const int e = lane + 64 * j;
                p = fmaf(s_agg[e], row[e], p);
            }
        }
        #pragma unroll
        for (int off = 32; off; off >>= 1) p += __shfl_down(p, off);
        if (lane == 0) s_score[m] = (idx >= 0) ? p * (1.f / 16.f) : -6.25e8f;
    }
    __syncthreads();

    float mx = -INFINITY;
    #pragma unroll
    for (int m = 0; m < MNB; ++m) mx = fmaxf(mx, s_score[m]);
    float w[MNB];
    float denom = 0.f;
    #pragma unroll
    for (int m = 0; m < MNB; ++m) { w[m] = __expf(s_score[m] - mx); denom += w[m]; }
    const float inv = 1.f / denom;

    float c = 0.f;
    #pragma unroll
    for (int m = 0; m < MNB; ++m) {
        const int idx = s_idx[m];
        if (idx >= 0) c = fmaf(w[m] * inv, agg[(size_t)idx * DIM + t], c);
    }
    ctx[(size_t)n * DIM + t] = c;
}

// ---------------------------------------------------------------------------
// Kernel 2: decode_attribute = sigmoid([node|ctx] @ W + b)  (f32, 64x64 tiles)
// ---------------------------------------------------------------------------
__global__ __launch_bounds__(256) void attr_kernel(
    const float* __restrict__ node,
    const float* __restrict__ ctx,
    const float* __restrict__ W,
    const float* __restrict__ bias,
    float* __restrict__ out)
{
    const int bi = blockIdx.x;
    const int bj = blockIdx.y;
    const int t = threadIdx.x;
    const int tx = t & 15, ty = t >> 4;

    __shared__ float s_a[16][64];
    __shared__ float s_b[16][64];

    float acc[4][4] = {};

    const int row_l = t >> 2;
    const int quad  = t & 3;
    const int gi = bi * 64 + row_l;
    const int brow  = t >> 4;
    const int bcol4 = (t & 15) * 4;

    for (int kc = 0; kc < 32; ++kc) {
        const float* Abase = (kc < 16) ? node : ctx;
        const int koff = (kc & 15) * 16;
        float4 av = make_float4(0.f, 0.f, 0.f, 0.f);
        if (gi < NNODES)
            av = *(const float4*)&Abase[(size_t)gi * DIM + koff + quad * 4];
        float4 bv = *(const float4*)&W[(size_t)(kc * 16 + brow) * DIM + bj * 64 + bcol4];

        __syncthreads();
        s_a[quad * 4 + 0][row_l] = av.x;
        s_a[quad * 4 + 1][row_l] = av.y;
        s_a[quad * 4 + 2][row_l] = av.z;
        s_a[quad * 4 + 3][row_l] = av.w;
        *(float4*)&s_b[brow][bcol4] = bv;
        __syncthreads();

        #pragma unroll
        for (int kk = 0; kk < 16; ++kk) {
            float4 a4 = *(const float4*)&s_a[kk][ty * 4];
            float4 b4 = *(const float4*)&s_b[kk][tx * 4];
            float a[4] = {a4.x, a4.y, a4.z, a4.w};
            float b[4] = {b4.x, b4.y, b4.z, b4.w};
            #pragma unroll
            for (int u = 0; u < 4; ++u)
                #pragma unroll
                for (int v = 0; v < 4; ++v)
                    acc[u][v] = fmaf(a[u], b[v], acc[u][v]);
        }
    }

    const int r0 = bi * 64 + ty * 4;
    const int c0 = bj * 64 + tx * 4;
    float4 bb = *(const float4*)&bias[c0];
    float bvals[4] = {bb.x, bb.y, bb.z, bb.w};
    #pragma unroll
    for (int u = 0; u < 4; ++u) {
        if (r0 + u < NNODES) {
            float4 val;
            val.x = 1.f / (1.f + __expf(-(acc[u][0] + bvals[0])));
            val.y = 1.f / (1.f + __expf(-(acc[u][1] + bvals[1])));
            val.z = 1.f / (1.f + __expf(-(acc[u][2] + bvals[2])));
            val.w = 1.f / (1.f + __expf(-(acc[u][3] + bvals[3])));
            *(float4*)&out[(size_t)(r0 + u) * DIM + c0] = val;
        }
    }
}

// ---------------------------------------------------------------------------
// Kernel 3: decode_adj = sigmoid(agg @ agg^T) via split-bf16 3-pass MFMA.
// 128x128 tile, 4 waves (2x2), 4x4 frags of 16x16x32 per wave. Upper triangle
// only; both tile images written via LDS so all global stores are 512B rows.
// ---------------------------------------------------------------------------
#define LDS_AH 0
#define LDS_AL 16384
#define LDS_BH 32768
#define LDS_BL 49152

__global__ __launch_bounds__(256, 2) void adj_mfma_kernel(
    const unsigned short* __restrict__ aggh,
    const unsigned short* __restrict__ aggl,
    float* __restrict__ out)
{
    const int bj = blockIdx.x;
    const int bi = blockIdx.y;
    if (bi > bj) return;

    __shared__ __align__(16) char lds[65536];

    const int t = threadIdx.x;
    const int l = t & 63;
    const int w = t >> 6;
    const int wm = w >> 1;            // wave row (0,1)
    const int wn = w & 1;             // wave col (0,1)

    // staging assignment: 2 threads per tile row
    const int srow = t >> 1;          // 0..127
    const int shalf = t & 1;
    const int rowA = min(bi * 128 + srow, NNODES - 1);
    const int rowB = min(bj * 128 + srow, NNODES - 1);
    const size_t offA = (size_t)rowA * DIM;
    const size_t offB = (size_t)rowB * DIM;

    f32x4 acc[4][4] = {};

    for (int kb = 0; kb < DIM; kb += 64) {
        __syncthreads();
        #pragma unroll
        for (int c = 0; c < 4; ++c) {
            const int k8 = shalf * 4 + c;                 // 16B chunk index 0..7
            const int chp = k8 ^ (srow & 7);              // XOR swizzle
            uint4 vah = *(const uint4*)&aggh[offA + kb + k8 * 8];
            uint4 val = *(const uint4*)&aggl[offA + kb + k8 * 8];
            uint4 vbh = *(const uint4*)&aggh[offB + kb + k8 * 8];
            uint4 vbl = *(const uint4*)&aggl[offB + kb + k8 * 8];
            *(uint4*)&lds[LDS_AH + srow * 128 + chp * 16] = vah;
            *(uint4*)&lds[LDS_AL + srow * 128 + chp * 16] = val;
            *(uint4*)&lds[LDS_BH + srow * 128 + chp * 16] = vbh;
            *(uint4*)&lds[LDS_BL + srow * 128 + chp * 16] = vbl;
        }
        __syncthreads();

        #pragma unroll
        for (int s = 0; s < 2; ++s) {
            bf16x8 ah[4], al[4], bh[4], bl[4];
            #pragma unroll
            for (int m = 0; m < 4; ++m) {
                const int ra = wm * 64 + m * 16 + (l & 15);
                const int ca = (s * 4 + (l >> 4)) ^ (ra & 7);
                ah[m] = *(const bf16x8*)&lds[LDS_AH + ra * 128 + ca * 16];
                al[m] = *(const bf16x8*)&lds[LDS_AL + ra * 128 + ca * 16];
                const int rb = wn * 64 + m * 16 + (l & 15);
                const int cb = (s * 4 + (l >> 4)) ^ (rb & 7);
                bh[m] = *(const bf16x8*)&lds[LDS_BH + rb * 128 + cb * 16];
                bl[m] = *(const bf16x8*)&lds[LDS_BL + rb * 128 + cb * 16];
            }
            #pragma unroll
            for (int m = 0; m < 4; ++m)
                #pragma unroll
                for (int n = 0; n < 4; ++n) {
                    acc[m][n] = __builtin_amdgcn_mfma_f32_16x16x32_bf16(ah[m], bh[n], acc[m][n], 0, 0, 0);
                    acc[m][n] = __builtin_amdgcn_mfma_f32_16x16x32_bf16(ah[m], bl[n], acc[m][n], 0, 0, 0);
                    acc[m][n] = __builtin_amdgcn_mfma_f32_16x16x32_bf16(al[m], bh[n], acc[m][n], 0, 0, 0);
                }
        }
    }

    // sigmoid in-register
    #pragma unroll
    for (int m = 0; m < 4; ++m)
        #pragma unroll
        for (int n = 0; n < 4; ++n)
            #pragma unroll
            for (int j = 0; j < 4; ++j)
                acc[m][n][j] = 1.f / (1.f + __expf(-acc[m][n][j]));

    float* sf = (float*)lds;

    // ---- pass 1: normal orientation [row][col], coalesced 512B row writes
    __syncthreads();
    #pragma unroll
    for (int m = 0; m < 4; ++m)
        #pragma unroll
        for (int n = 0; n < 4; ++n)
            #pragma unroll
            for (int j = 0; j < 4; ++j) {
                const int r = wm * 64 + m * 16 + (l >> 4) * 4 + j;
                const int c = wn * 64 + n * 16 + (l & 15);
                sf[r * 128 + c] = acc[m][n][j];
            }
    __syncthreads();
    {
        const int r = t >> 1, h = t & 1;
        const int gr = bi * 128 + r;
        const int gc0 = bj * 128 + h * 64;
        if (gr < NNODES) {
            if (gc0 + 63 < NNODES) {
                #pragma unroll
                for (int c4 = 0; c4 < 16; ++c4) {
                    f32x4 v = *(f32x4*)&sf[r * 128 + h * 64 + c4 * 4];
                    __builtin_nontemporal_store(v, (f32x4*)&out[(size_t)gr * NNODES + gc0 + c4 * 4]);
                }
            } else {
                for (int c = 0; c < 64; ++c)
                    if (gc0 + c < NNODES)
                        out[(size_t)gr * NNODES + gc0 + c] = sf[r * 128 + h * 64 + c];
            }
        }
    }

    // ---- pass 2: transposed image for the mirror tile (skip on diagonal)
    if (bi != bj) {
        __syncthreads();
        #pragma unroll
        for (int m = 0; m < 4; ++m)
            #pragma unroll
            for (int n = 0; n < 4; ++n)
                #pragma unroll
                for (int j = 0; j < 4; ++j) {
                    const int r = wm * 64 + m * 16 + (l >> 4) * 4 + j;
                    const int c = wn * 64 + n * 16 + (l & 15);
                    // swizzled transpose: row-group XORed by col&7
                    sf[c * 128 + (((r >> 2) ^ (c & 7)) << 2) + (r & 3)] = acc[m][n][j];
                }
        __syncthreads();
        {
            const int cr = t >> 1, h = t & 1;
            const int gr2 = bj * 128 + cr;          // transposed row = original col
            const int gc2 = bi * 128 + h * 64;      // cols always < N here (bi<78)
            if (gr2 < NNODES) {
                #pragma unroll
                for (int g4 = 0; g4 < 16; ++g4) {
                    const int g = h * 16 + g4;
                    f32x4 v = *(f32x4*)&sf[cr * 128 + ((g ^ (cr & 7)) << 2)];
                    __builtin_nontemporal_store(v, (f32x4*)&out[(size_t)gr2 * NNODES + gc2 + g4 * 4]);
                }
            }
        }
    }
}

extern "C" void kernel_launch(void* const* d_in, const int* in_sizes, int n_in,
                              void* d_out, int out_size, void* d_ws, size_t ws_size,
                              hipStream_t stream) {
    const float* node = (const float*)d_in[0];   // [N,256]
    const float* agg  = (const float*)d_in[1];   // [N,256]
    const int*   nb   = (const int*)d_in[2];     // [N,32]
    const float* W    = (const float*)d_in[3];   // [512,256]
    const float* bias = (const float*)d_in[4];   // [256]

    float* out_attr = (float*)d_out;
    float* out_adj  = (float*)d_out + (size_t)NNODES * DIM;

    float* ctx = (float*)d_ws;                                        // 10.24 MB
    unsigned short* aggh = (unsigned short*)((char*)d_ws + 10240000); // 5.12 MB
    unsigned short* aggl = aggh + (size_t)NNODES * DIM;               // 5.12 MB

    split_kernel<<<(NNODES * DIM / 8 + 255) / 256, 256, 0, stream>>>(agg, aggh, aggl);

    attn_ctx_kernel<<<NNODES, 256, 0, stream>>>(agg, nb, ctx);

    dim3 g2(157, 4);
    attr_kernel<<<g2, 256, 0, stream>>>(node, ctx, W, bias, out_attr);

    dim3 g3(NT, NT);
    adj_mfma_kernel<<<g3, 256, 0, stream>>>(aggh, aggl, out_adj);
}

// Round 4
// 297.585 us; speedup vs baseline: 4.6354x; 4.6354x over previous
//
#include <hip/hip_runtime.h>
#include <cstdint>
#include <cstddef>

#define NNODES 10000
#define DIM 256
#define MNB 32
#define NT 79   // ceil(10000/128)

typedef __attribute__((ext_vector_type(8))) short bf16x8;
typedef __attribute__((ext_vector_type(4))) float f32x4;

// ---------------------------------------------------------------------------
// Kernel 0: split agg (f32) into bf16 hi/lo arrays (RNE both).
// ---------------------------------------------------------------------------
__device__ inline unsigned short bf16_rne(float f) {
    unsigned int u = __float_as_uint(f);
    u = u + 0x7FFFu + ((u >> 16) & 1u);
    return (unsigned short)(u >> 16);
}

__global__ __launch_bounds__(256) void split_kernel(
    const float* __restrict__ agg,
    unsigned short* __restrict__ hi,
    unsigned short* __restrict__ lo)
{
    const int i = blockIdx.x * 256 + threadIdx.x;      // 8 floats per thread
    if (i >= NNODES * DIM / 8) return;
    float4 a = ((const float4*)agg)[i * 2];
    float4 b = ((const float4*)agg)[i * 2 + 1];
    float f[8] = {a.x, a.y, a.z, a.w, b.x, b.y, b.z, b.w};
    unsigned int hp[4], lp[4];
    #pragma unroll
    for (int j = 0; j < 4; ++j) {
        unsigned short h0 = bf16_rne(f[2 * j]);
        unsigned short h1 = bf16_rne(f[2 * j + 1]);
        float hf0 = __uint_as_float((unsigned int)h0 << 16);
        float hf1 = __uint_as_float((unsigned int)h1 << 16);
        unsigned short l0 = bf16_rne(f[2 * j] - hf0);
        unsigned short l1 = bf16_rne(f[2 * j + 1] - hf1);
        hp[j] = (unsigned int)h0 | ((unsigned int)h1 << 16);
        lp[j] = (unsigned int)l0 | ((unsigned int)l1 << 16);
    }
    ((uint4*)hi)[i] = make_uint4(hp[0], hp[1], hp[2], hp[3]);
    ((uint4*)lo)[i] = make_uint4(lp[0], lp[1], lp[2], lp[3]);
}

// ---------------------------------------------------------------------------
// Kernel 1: attention context. One block (256 thr) per node.
// ---------------------------------------------------------------------------
__global__ __launch_bounds__(256) void attn_ctx_kernel(
    const float* __restrict__ agg,
    const int* __restrict__ nb_id,
    float* __restrict__ ctx)
{
    const int n = blockIdx.x;
    const int t = threadIdx.x;
    __shared__ float s_agg[DIM];
    __shared__ float s_score[MNB];
    __shared__ int   s_idx[MNB];

    s_agg[t] = agg[(size_t)n * DIM + t];
    if (t < MNB) s_idx[t] = nb_id[n * MNB + t];
    __syncthreads();

    const int wave = t >> 6;
    const int lane = t & 63;

    #pragma unroll
    for (int mi = 0; mi < 8; ++mi) {
        const int m = wave * 8 + mi;
        const int idx = s_idx[m];
        float p = 0.f;
        if (idx >= 0) {
            const float* row = agg + (size_t)idx * DIM;
            #pragma unroll
            for (int j = 0; j < 4; ++j) {
                const int e = lane + 64 * j;
                p = fmaf(s_agg[e], row[e], p);
            }
        }
        #pragma unroll
        for (int off = 32; off; off >>= 1) p += __shfl_down(p, off);
        if (lane == 0) s_score[m] = (idx >= 0) ? p * (1.f / 16.f) : -6.25e8f;
    }
    __syncthreads();

    float mx = -INFINITY;
    #pragma unroll
    for (int m = 0; m < MNB; ++m) mx = fmaxf(mx, s_score[m]);
    float w[MNB];
    float denom = 0.f;
    #pragma unroll
    for (int m = 0; m < MNB; ++m) { w[m] = __expf(s_score[m] - mx); denom += w[m]; }
    const float inv = 1.f / denom;

    float c = 0.f;
    #pragma unroll
    for (int m = 0; m < MNB; ++m) {
        const int idx = s_idx[m];
        if (idx >= 0) c = fmaf(w[m] * inv, agg[(size_t)idx * DIM + t], c);
    }
    ctx[(size_t)n * DIM + t] = c;
}

// ---------------------------------------------------------------------------
// Kernel 2: decode_attribute = sigmoid([node|ctx] @ W + b)  (f32, 64x64 tiles)
// ---------------------------------------------------------------------------
__global__ __launch_bounds__(256) void attr_kernel(
    const float* __restrict__ node,
    const float* __restrict__ ctx,
    const float* __restrict__ W,
    const float* __restrict__ bias,
    float* __restrict__ out)
{
    const int bi = blockIdx.x;
    const int bj = blockIdx.y;
    const int t = threadIdx.x;
    const int tx = t & 15, ty = t >> 4;

    __shared__ float s_a[16][64];
    __shared__ float s_b[16][64];

    float acc[4][4] = {};

    const int row_l = t >> 2;
    const int quad  = t & 3;
    const int gi = bi * 64 + row_l;
    const int brow  = t >> 4;
    const int bcol4 = (t & 15) * 4;

    for (int kc = 0; kc < 32; ++kc) {
        const float* Abase = (kc < 16) ? node : ctx;
        const int koff = (kc & 15) * 16;
        float4 av = make_float4(0.f, 0.f, 0.f, 0.f);
        if (gi < NNODES)
            av = *(const float4*)&Abase[(size_t)gi * DIM + koff + quad * 4];
        float4 bv = *(const float4*)&W[(size_t)(kc * 16 + brow) * DIM + bj * 64 + bcol4];

        __syncthreads();
        s_a[quad * 4 + 0][row_l] = av.x;
        s_a[quad * 4 + 1][row_l] = av.y;
        s_a[quad * 4 + 2][row_l] = av.z;
        s_a[quad * 4 + 3][row_l] = av.w;
        *(float4*)&s_b[brow][bcol4] = bv;
        __syncthreads();

        #pragma unroll
        for (int kk = 0; kk < 16; ++kk) {
            float4 a4 = *(const float4*)&s_a[kk][ty * 4];
            float4 b4 = *(const float4*)&s_b[kk][tx * 4];
            float a[4] = {a4.x, a4.y, a4.z, a4.w};
            float b[4] = {b4.x, b4.y, b4.z, b4.w};
            #pragma unroll
            for (int u = 0; u < 4; ++u)
                #pragma unroll
                for (int v = 0; v < 4; ++v)
                    acc[u][v] = fmaf(a[u], b[v], acc[u][v]);
        }
    }

    const int r0 = bi * 64 + ty * 4;
    const int c0 = bj * 64 + tx * 4;
    float4 bb = *(const float4*)&bias[c0];
    float bvals[4] = {bb.x, bb.y, bb.z, bb.w};
    #pragma unroll
    for (int u = 0; u < 4; ++u) {
        if (r0 + u < NNODES) {
            float4 val;
            val.x = 1.f / (1.f + __expf(-(acc[u][0] + bvals[0])));
            val.y = 1.f / (1.f + __expf(-(acc[u][1] + bvals[1])));
            val.z = 1.f / (1.f + __expf(-(acc[u][2] + bvals[2])));
            val.w = 1.f / (1.f + __expf(-(acc[u][3] + bvals[3])));
            *(float4*)&out[(size_t)(r0 + u) * DIM + c0] = val;
        }
    }
}

// ---------------------------------------------------------------------------
// Kernel 3: decode_adj = sigmoid(agg @ agg^T) via split-bf16 3-pass MFMA.
// 128x128 tile, 4 waves (2x2), 4x4 frags of 16x16x32 per wave. Upper triangle
// only. Write-out: each 32-lane half-wave stores one contiguous 512B row
// segment (lane&31 = float4 chunk, lane>>5 = row) -- full-line coverage.
// ---------------------------------------------------------------------------
#define LDS_AH 0
#define LDS_AL 16384
#define LDS_BH 32768
#define LDS_BL 49152

__global__ __launch_bounds__(256, 2) void adj_mfma_kernel(
    const unsigned short* __restrict__ aggh,
    const unsigned short* __restrict__ aggl,
    float* __restrict__ out)
{
    const int bj = blockIdx.x;
    const int bi = blockIdx.y;
    if (bi > bj) return;

    __shared__ __align__(16) char lds[65536];

    const int t = threadIdx.x;
    const int l = t & 63;
    const int w = t >> 6;
    const int wm = w >> 1;            // wave row (0,1)
    const int wn = w & 1;             // wave col (0,1)

    // staging assignment: 2 threads per tile row
    const int srow = t >> 1;          // 0..127
    const int shalf = t & 1;
    const int rowA = min(bi * 128 + srow, NNODES - 1);
    const int rowB = min(bj * 128 + srow, NNODES - 1);
    const size_t offA = (size_t)rowA * DIM;
    const size_t offB = (size_t)rowB * DIM;

    f32x4 acc[4][4] = {};

    for (int kb = 0; kb < DIM; kb += 64) {
        __syncthreads();
        #pragma unroll
        for (int c = 0; c < 4; ++c) {
            const int k8 = shalf * 4 + c;                 // 16B chunk index 0..7
            const int chp = k8 ^ (srow & 7);              // XOR swizzle
            uint4 vah = *(const uint4*)&aggh[offA + kb + k8 * 8];
            uint4 val = *(const uint4*)&aggl[offA + kb + k8 * 8];
            uint4 vbh = *(const uint4*)&aggh[offB + kb + k8 * 8];
            uint4 vbl = *(const uint4*)&aggl[offB + kb + k8 * 8];
            *(uint4*)&lds[LDS_AH + srow * 128 + chp * 16] = vah;
            *(uint4*)&lds[LDS_AL + srow * 128 + chp * 16] = val;
            *(uint4*)&lds[LDS_BH + srow * 128 + chp * 16] = vbh;
            *(uint4*)&lds[LDS_BL + srow * 128 + chp * 16] = vbl;
        }
        __syncthreads();

        #pragma unroll
        for (int s = 0; s < 2; ++s) {
            bf16x8 ah[4], al[4], bh[4], bl[4];
            #pragma unroll
            for (int m = 0; m < 4; ++m) {
                const int ra = wm * 64 + m * 16 + (l & 15);
                const int ca = (s * 4 + (l >> 4)) ^ (ra & 7);
                ah[m] = *(const bf16x8*)&lds[LDS_AH + ra * 128 + ca * 16];
                al[m] = *(const bf16x8*)&lds[LDS_AL + ra * 128 + ca * 16];
                const int rb = wn * 64 + m * 16 + (l & 15);
                const int cb = (s * 4 + (l >> 4)) ^ (rb & 7);
                bh[m] = *(const bf16x8*)&lds[LDS_BH + rb * 128 + cb * 16];
                bl[m] = *(const bf16x8*)&lds[LDS_BL + rb * 128 + cb * 16];
            }
            #pragma unroll
            for (int m = 0; m < 4; ++m)
                #pragma unroll
                for (int n = 0; n < 4; ++n) {
                    acc[m][n] = __builtin_amdgcn_mfma_f32_16x16x32_bf16(ah[m], bh[n], acc[m][n], 0, 0, 0);
                    acc[m][n] = __builtin_amdgcn_mfma_f32_16x16x32_bf16(ah[m], bl[n], acc[m][n], 0, 0, 0);
                    acc[m][n] = __builtin_amdgcn_mfma_f32_16x16x32_bf16(al[m], bh[n], acc[m][n], 0, 0, 0);
                }
        }
    }

    // sigmoid in-register
    #pragma unroll
    for (int m = 0; m < 4; ++m)
        #pragma unroll
        for (int n = 0; n < 4; ++n)
            #pragma unroll
            for (int j = 0; j < 4; ++j)
                acc[m][n][j] = 1.f / (1.f + __expf(-acc[m][n][j]));

    float* sf = (float*)lds;

    // ---- pass 1: normal orientation [row][col]
    __syncthreads();
    #pragma unroll
    for (int m = 0; m < 4; ++m)
        #pragma unroll
        for (int n = 0; n < 4; ++n)
            #pragma unroll
            for (int j = 0; j < 4; ++j) {
                const int r = wm * 64 + m * 16 + (l >> 4) * 4 + j;
                const int c = wn * 64 + n * 16 + (l & 15);
                sf[r * 128 + c] = acc[m][n][j];
            }
    __syncthreads();
    {
        const int c4 = t & 31;                 // float4 chunk within row
        const int gc = bj * 128 + c4 * 4;      // N%4==0 -> chunk fully in or out
        #pragma unroll
        for (int it = 0; it < 16; ++it) {
            const int r = it * 8 + (t >> 5);
            const int gr = bi * 128 + r;
            if (gr < NNODES && gc < NNODES) {
                f32x4 v = *(f32x4*)&sf[r * 128 + c4 * 4];
                __builtin_nontemporal_store(v, (f32x4*)&out[(size_t)gr * NNODES + gc]);
            }
        }
    }

    // ---- pass 2: transposed image for the mirror tile (skip on diagonal)
    if (bi != bj) {
        __syncthreads();
        #pragma unroll
        for (int m = 0; m < 4; ++m)
            #pragma unroll
            for (int n = 0; n < 4; ++n)
                #pragma unroll
                for (int j = 0; j < 4; ++j) {
                    const int r = wm * 64 + m * 16 + (l >> 4) * 4 + j;
                    const int c = wn * 64 + n * 16 + (l & 15);
                    // transposed layout [c][r], row-group of 4 XORed by c&7
                    sf[c * 128 + (((r >> 2) ^ (c & 7)) << 2) + (r & 3)] = acc[m][n][j];
                }
        __syncthreads();
        {
            const int g = t & 31;              // float4 chunk within transposed row
            const int gc2 = bi * 128 + g * 4;  // bi <= 77 here -> always in range
            #pragma unroll
            for (int it = 0; it < 16; ++it) {
                const int rt = it * 8 + (t >> 5);   // transposed row = original col
                const int gr2 = bj * 128 + rt;
                if (gr2 < NNODES) {
                    f32x4 v = *(f32x4*)&sf[rt * 128 + ((g ^ (rt & 7)) << 2)];
                    __builtin_nontemporal_store(v, (f32x4*)&out[(size_t)gr2 * NNODES + gc2]);
                }
            }
        }
    }
}

extern "C" void kernel_launch(void* const* d_in, const int* in_sizes, int n_in,
                              void* d_out, int out_size, void* d_ws, size_t ws_size,
                              hipStream_t stream) {
    const float* node = (const float*)d_in[0];   // [N,256]
    const float* agg  = (const float*)d_in[1];   // [N,256]
    const int*   nb   = (const int*)d_in[2];     // [N,32]
    const float* W    = (const float*)d_in[3];   // [512,256]
    const float* bias = (const float*)d_in[4];   // [256]

    float* out_attr = (float*)d_out;
    float* out_adj  = (float*)d_out + (size_t)NNODES * DIM;

    float* ctx = (float*)d_ws;                                        // 10.24 MB
    unsigned short* aggh = (unsigned short*)((char*)d_ws + 10240000); // 5.12 MB
    unsigned short* aggl = aggh + (size_t)NNODES * DIM;               // 5.12 MB

    split_kernel<<<(NNODES * DIM / 8 + 255) / 256, 256, 0, stream>>>(agg, aggh, aggl);

    attn_ctx_kernel<<<NNODES, 256, 0, stream>>>(agg, nb, ctx);

    dim3 g2(157, 4);
    attr_kernel<<<g2, 256, 0, stream>>>(node, ctx, W, bias, out_attr);

    dim3 g3(NT, NT);
    adj_mfma_kernel<<<g3, 256, 0, stream>>>(aggh, aggl, out_adj);
}

// Round 5
// 255.528 us; speedup vs baseline: 5.3983x; 1.1646x over previous
//
#include <hip/hip_runtime.h>
#include <cstdint>
#include <cstddef>

#define NNODES 10000
#define DIM 256
#define MNB 32
#define NT 79   // ceil(10000/128)

typedef __attribute__((ext_vector_type(8))) short bf16x8;
typedef __attribute__((ext_vector_type(4))) float f32x4;

// ---------------------------------------------------------------------------
// Kernel 0: split f32 array into bf16 hi/lo arrays (RNE both).
// ---------------------------------------------------------------------------
__device__ inline unsigned short bf16_rne(float f) {
    unsigned int u = __float_as_uint(f);
    u = u + 0x7FFFu + ((u >> 16) & 1u);
    return (unsigned short)(u >> 16);
}

__global__ __launch_bounds__(256) void split_kernel(
    const float* __restrict__ in,
    unsigned short* __restrict__ hi,
    unsigned short* __restrict__ lo,
    int count8)
{
    const int i = blockIdx.x * 256 + threadIdx.x;      // 8 floats per thread
    if (i >= count8) return;
    float4 a = ((const float4*)in)[i * 2];
    float4 b = ((const float4*)in)[i * 2 + 1];
    float f[8] = {a.x, a.y, a.z, a.w, b.x, b.y, b.z, b.w};
    unsigned int hp[4], lp[4];
    #pragma unroll
    for (int j = 0; j < 4; ++j) {
        unsigned short h0 = bf16_rne(f[2 * j]);
        unsigned short h1 = bf16_rne(f[2 * j + 1]);
        float hf0 = __uint_as_float((unsigned int)h0 << 16);
        float hf1 = __uint_as_float((unsigned int)h1 << 16);
        unsigned short l0 = bf16_rne(f[2 * j] - hf0);
        unsigned short l1 = bf16_rne(f[2 * j + 1] - hf1);
        hp[j] = (unsigned int)h0 | ((unsigned int)h1 << 16);
        lp[j] = (unsigned int)l0 | ((unsigned int)l1 << 16);
    }
    ((uint4*)hi)[i] = make_uint4(hp[0], hp[1], hp[2], hp[3]);
    ((uint4*)lo)[i] = make_uint4(lp[0], lp[1], lp[2], lp[3]);
}

// ---------------------------------------------------------------------------
// Kernel 0b: W [512,256] -> WT hi/lo [256,512] (transpose + split). Tiny.
// ---------------------------------------------------------------------------
__global__ __launch_bounds__(256) void wt_split_kernel(
    const float* __restrict__ W,
    unsigned short* __restrict__ wth,
    unsigned short* __restrict__ wtl)
{
    const int r = blockIdx.x;        // 0..255 : WT row = W col
    const int t = threadIdx.x;       // 0..255
    #pragma unroll
    for (int h = 0; h < 2; ++h) {
        const int k = h * 256 + t;   // 0..511
        float v = W[(size_t)k * DIM + r];
        unsigned short hh = bf16_rne(v);
        float hf = __uint_as_float((unsigned int)hh << 16);
        unsigned short ll = bf16_rne(v - hf);
        wth[(size_t)r * 512 + k] = hh;
        wtl[(size_t)r * 512 + k] = ll;
    }
}

// ---------------------------------------------------------------------------
// Kernel 1: attention context. One block per node. Neighbor rows staged in
// LDS (32KB) during the score pass and reused for the context pass.
// Emits ctx directly as bf16 hi/lo (consumed by the MFMA attr kernel).
// ---------------------------------------------------------------------------
__global__ __launch_bounds__(256) void attn_ctx_kernel(
    const float* __restrict__ agg,
    const int* __restrict__ nb_id,
    unsigned short* __restrict__ ctxh,
    unsigned short* __restrict__ ctxl)
{
    const int n = blockIdx.x;
    const int t = threadIdx.x;
    __shared__ float4 s_nb[MNB][64];   // 32 KB: gathered neighbor rows
    __shared__ float s_score[MNB];
    __shared__ int   s_idx[MNB];

    if (t < MNB) s_idx[t] = nb_id[n * MNB + t];
    __syncthreads();

    const int wave = t >> 6;
    const int lane = t & 63;

    const float4 q = ((const float4*)agg)[(size_t)n * 64 + lane];

    // each wave: 8 neighbors. One float4 per lane per row (fully coalesced).
    #pragma unroll
    for (int mi = 0; mi < 8; ++mi) {
        const int m = wave * 8 + mi;
        const int idx = s_idx[m];
        float4 v = make_float4(0.f, 0.f, 0.f, 0.f);
        if (idx >= 0) v = ((const float4*)agg)[(size_t)idx * 64 + lane];
        s_nb[m][lane] = v;
        float p = q.x * v.x + q.y * v.y + q.z * v.z + q.w * v.w;
        #pragma unroll
        for (int off = 32; off; off >>= 1) p += __shfl_down(p, off);
        if (lane == 0) s_score[m] = (idx >= 0) ? p * (1.f / 16.f) : -6.25e8f;
    }
    __syncthreads();

    // redundant 32-wide softmax in every thread
    float mx = -INFINITY;
    #pragma unroll
    for (int m = 0; m < MNB; ++m) mx = fmaxf(mx, s_score[m]);
    float w[MNB];
    float denom = 0.f;
    #pragma unroll
    for (int m = 0; m < MNB; ++m) { w[m] = __expf(s_score[m] - mx); denom += w[m]; }
    const float inv = 1.f / denom;

    // context: thread t owns column t; rows come from LDS (2-way free reads)
    const float* nbf = (const float*)s_nb;
    float c = 0.f;
    #pragma unroll
    for (int m = 0; m < MNB; ++m)
        c = fmaf(w[m] * inv, nbf[m * DIM + t], c);

    unsigned short h = bf16_rne(c);
    float hf = __uint_as_float((unsigned int)h << 16);
    unsigned short l = bf16_rne(c - hf);
    ctxh[(size_t)n * DIM + t] = h;
    ctxl[(size_t)n * DIM + t] = l;
}

// ---------------------------------------------------------------------------
// Shared LDS layout for both MFMA kernels
// ---------------------------------------------------------------------------
#define LDS_AH 0
#define LDS_AL 16384
#define LDS_BH 32768
#define LDS_BL 49152

// ---------------------------------------------------------------------------
// Kernel 2: decode_attribute = sigmoid([node|ctx] @ W + b) via split-bf16
// 3-pass MFMA. Tile 128x128, 2x2 waves, K=512 (node half then ctx half).
// B operand staged from WT [256,512] rows (= output cols), k-contiguous.
// ---------------------------------------------------------------------------
__global__ __launch_bounds__(256, 2) void attr_mfma_kernel(
    const unsigned short* __restrict__ nodeh,
    const unsigned short* __restrict__ nodel,
    const unsigned short* __restrict__ ctxh,
    const unsigned short* __restrict__ ctxl,
    const unsigned short* __restrict__ wth,
    const unsigned short* __restrict__ wtl,
    const float* __restrict__ bias,
    float* __restrict__ out)
{
    const int bj = blockIdx.x;        // 0..1   (output cols, 128 each)
    const int bi = blockIdx.y;        // 0..78  (output rows, 128 each)

    __shared__ __align__(16) char lds[65536];

    const int t = threadIdx.x;
    const int l = t & 63;
    const int w = t >> 6;
    const int wm = w >> 1;
    const int wn = w & 1;

    const int srow = t >> 1;          // 0..127
    const int shalf = t & 1;
    const int rowA = min(bi * 128 + srow, NNODES - 1);
    const size_t offA = (size_t)rowA * DIM;
    const int rowB = bj * 128 + srow;            // < 256 always
    const size_t offB = (size_t)rowB * 512;

    f32x4 acc[4][4] = {};

    for (int kb = 0; kb < 512; kb += 64) {
        const unsigned short* aH = (kb < 256) ? nodeh : ctxh;
        const unsigned short* aL = (kb < 256) ? nodel : ctxl;
        const int koff = kb & 255;
        __syncthreads();
        #pragma unroll
        for (int c = 0; c < 4; ++c) {
            const int k8 = shalf * 4 + c;                 // 16B chunk 0..7
            const int chp = k8 ^ (srow & 7);              // XOR swizzle
            uint4 vah = *(const uint4*)&aH[offA + koff + k8 * 8];
            uint4 val = *(const uint4*)&aL[offA + koff + k8 * 8];
            uint4 vbh = *(const uint4*)&wth[offB + kb + k8 * 8];
            uint4 vbl = *(const uint4*)&wtl[offB + kb + k8 * 8];
            *(uint4*)&lds[LDS_AH + srow * 128 + chp * 16] = vah;
            *(uint4*)&lds[LDS_AL + srow * 128 + chp * 16] = val;
            *(uint4*)&lds[LDS_BH + srow * 128 + chp * 16] = vbh;
            *(uint4*)&lds[LDS_BL + srow * 128 + chp * 16] = vbl;
        }
        __syncthreads();

        #pragma unroll
        for (int s = 0; s < 2; ++s) {
            bf16x8 ah[4], al[4], bh[4], bl[4];
            #pragma unroll
            for (int m = 0; m < 4; ++m) {
                const int ra = wm * 64 + m * 16 + (l & 15);
                const int ca = (s * 4 + (l >> 4)) ^ (ra & 7);
                ah[m] = *(const bf16x8*)&lds[LDS_AH + ra * 128 + ca * 16];
                al[m] = *(const bf16x8*)&lds[LDS_AL + ra * 128 + ca * 16];
                const int rb = wn * 64 + m * 16 + (l & 15);
                const int cb = (s * 4 + (l >> 4)) ^ (rb & 7);
                bh[m] = *(const bf16x8*)&lds[LDS_BH + rb * 128 + cb * 16];
                bl[m] = *(const bf16x8*)&lds[LDS_BL + rb * 128 + cb * 16];
            }
            #pragma unroll
            for (int m = 0; m < 4; ++m)
                #pragma unroll
                for (int n = 0; n < 4; ++n) {
                    acc[m][n] = __builtin_amdgcn_mfma_f32_16x16x32_bf16(ah[m], bh[n], acc[m][n], 0, 0, 0);
                    acc[m][n] = __builtin_amdgcn_mfma_f32_16x16x32_bf16(ah[m], bl[n], acc[m][n], 0, 0, 0);
                    acc[m][n] = __builtin_amdgcn_mfma_f32_16x16x32_bf16(al[m], bh[n], acc[m][n], 0, 0, 0);
                }
        }
    }

    // bias + sigmoid
    float bias_v[4];
    #pragma unroll
    for (int n = 0; n < 4; ++n)
        bias_v[n] = bias[bj * 128 + wn * 64 + n * 16 + (l & 15)];
    #pragma unroll
    for (int m = 0; m < 4; ++m)
        #pragma unroll
        for (int n = 0; n < 4; ++n)
            #pragma unroll
            for (int j = 0; j < 4; ++j)
                acc[m][n][j] = 1.f / (1.f + __expf(-(acc[m][n][j] + bias_v[n])));

    float* sf = (float*)lds;
    __syncthreads();
    #pragma unroll
    for (int m = 0; m < 4; ++m)
        #pragma unroll
        for (int n = 0; n < 4; ++n)
            #pragma unroll
            for (int j = 0; j < 4; ++j) {
                const int r = wm * 64 + m * 16 + (l >> 4) * 4 + j;
                const int c = wn * 64 + n * 16 + (l & 15);
                sf[r * 128 + c] = acc[m][n][j];
            }
    __syncthreads();
    {
        const int c4 = t & 31;                  // float4 chunk within 128-col tile
        const int gc = bj * 128 + c4 * 4;       // < 256 always
        #pragma unroll
        for (int it = 0; it < 16; ++it) {
            const int r = it * 8 + (t >> 5);
            const int gr = bi * 128 + r;
            if (gr < NNODES) {
                float4 v = *(float4*)&sf[r * 128 + c4 * 4];
                *(float4*)&out[(size_t)gr * DIM + gc] = v;
            }
        }
    }
}

// ---------------------------------------------------------------------------
// Kernel 3: decode_adj = sigmoid(agg @ agg^T) via split-bf16 3-pass MFMA.
// (unchanged from R4 — validated)
// ---------------------------------------------------------------------------
__global__ __launch_bounds__(256, 2) void adj_mfma_kernel(
    const unsigned short* __restrict__ aggh,
    const unsigned short* __restrict__ aggl,
    float* __restrict__ out)
{
    const int bj = blockIdx.x;
    const int bi = blockIdx.y;
    if (bi > bj) return;

    __shared__ __align__(16) char lds[65536];

    const int t = threadIdx.x;
    const int l = t & 63;
    const int w = t >> 6;
    const int wm = w >> 1;
    const int wn = w & 1;

    const int srow = t >> 1;
    const int shalf = t & 1;
    const int rowA = min(bi * 128 + srow, NNODES - 1);
    const int rowB = min(bj * 128 + srow, NNODES - 1);
    const size_t offA = (size_t)rowA * DIM;
    const size_t offB = (size_t)rowB * DIM;

    f32x4 acc[4][4] = {};

    for (int kb = 0; kb < DIM; kb += 64) {
        __syncthreads();
        #pragma unroll
        for (int c = 0; c < 4; ++c) {
            const int k8 = shalf * 4 + c;
            const int chp = k8 ^ (srow & 7);
            uint4 vah = *(const uint4*)&aggh[offA + kb + k8 * 8];
            uint4 val = *(const uint4*)&aggl[offA + kb + k8 * 8];
            uint4 vbh = *(const uint4*)&aggh[offB + kb + k8 * 8];
            uint4 vbl = *(const uint4*)&aggl[offB + kb + k8 * 8];
            *(uint4*)&lds[LDS_AH + srow * 128 + chp * 16] = vah;
            *(uint4*)&lds[LDS_AL + srow * 128 + chp * 16] = val;
            *(uint4*)&lds[LDS_BH + srow * 128 + chp * 16] = vbh;
            *(uint4*)&lds[LDS_BL + srow * 128 + chp * 16] = vbl;
        }
        __syncthreads();

        #pragma unroll
        for (int s = 0; s < 2; ++s) {
            bf16x8 ah[4], al[4], bh[4], bl[4];
            #pragma unroll
            for (int m = 0; m < 4; ++m) {
                const int ra = wm * 64 + m * 16 + (l & 15);
                const int ca = (s * 4 + (l >> 4)) ^ (ra & 7);
                ah[m] = *(const bf16x8*)&lds[LDS_AH + ra * 128 + ca * 16];
                al[m] = *(const bf16x8*)&lds[LDS_AL + ra * 128 + ca * 16];
                const int rb = wn * 64 + m * 16 + (l & 15);
                const int cb = (s * 4 + (l >> 4)) ^ (rb & 7);
                bh[m] = *(const bf16x8*)&lds[LDS_BH + rb * 128 + cb * 16];
                bl[m] = *(const bf16x8*)&lds[LDS_BL + rb * 128 + cb * 16];
            }
            #pragma unroll
            for (int m = 0; m < 4; ++m)
                #pragma unroll
                for (int n = 0; n < 4; ++n) {
                    acc[m][n] = __builtin_amdgcn_mfma_f32_16x16x32_bf16(ah[m], bh[n], acc[m][n], 0, 0, 0);
                    acc[m][n] = __builtin_amdgcn_mfma_f32_16x16x32_bf16(ah[m], bl[n], acc[m][n], 0, 0, 0);
                    acc[m][n] = __builtin_amdgcn_mfma_f32_16x16x32_bf16(al[m], bh[n], acc[m][n], 0, 0, 0);
                }
        }
    }

    #pragma unroll
    for (int m = 0; m < 4; ++m)
        #pragma unroll
        for (int n = 0; n < 4; ++n)
            #pragma unroll
            for (int j = 0; j < 4; ++j)
                acc[m][n][j] = 1.f / (1.f + __expf(-acc[m][n][j]));

    float* sf = (float*)lds;

    __syncthreads();
    #pragma unroll
    for (int m = 0; m < 4; ++m)
        #pragma unroll
        for (int n = 0; n < 4; ++n)
            #pragma unroll
            for (int j = 0; j < 4; ++j) {
                const int r = wm * 64 + m * 16 + (l >> 4) * 4 + j;
                const int c = wn * 64 + n * 16 + (l & 15);
                sf[r * 128 + c] = acc[m][n][j];
            }
    __syncthreads();
    {
        const int c4 = t & 31;
        const int gc = bj * 128 + c4 * 4;
        #pragma unroll
        for (int it = 0; it < 16; ++it) {
            const int r = it * 8 + (t >> 5);
            const int gr = bi * 128 + r;
            if (gr < NNODES && gc < NNODES) {
                f32x4 v = *(f32x4*)&sf[r * 128 + c4 * 4];
                __builtin_nontemporal_store(v, (f32x4*)&out[(size_t)gr * NNODES + gc]);
            }
        }
    }

    if (bi != bj) {
        __syncthreads();
        #pragma unroll
        for (int m = 0; m < 4; ++m)
            #pragma unroll
            for (int n = 0; n < 4; ++n)
                #pragma unroll
                for (int j = 0; j < 4; ++j) {
                    const int r = wm * 64 + m * 16 + (l >> 4) * 4 + j;
                    const int c = wn * 64 + n * 16 + (l & 15);
                    sf[c * 128 + (((r >> 2) ^ (c & 7)) << 2) + (r & 3)] = acc[m][n][j];
                }
        __syncthreads();
        {
            const int g = t & 31;
            const int gc2 = bi * 128 + g * 4;
            #pragma unroll
            for (int it = 0; it < 16; ++it) {
                const int rt = it * 8 + (t >> 5);
                const int gr2 = bj * 128 + rt;
                if (gr2 < NNODES) {
                    f32x4 v = *(f32x4*)&sf[rt * 128 + ((g ^ (rt & 7)) << 2)];
                    __builtin_nontemporal_store(v, (f32x4*)&out[(size_t)gr2 * NNODES + gc2]);
                }
            }
        }
    }
}

extern "C" void kernel_launch(void* const* d_in, const int* in_sizes, int n_in,
                              void* d_out, int out_size, void* d_ws, size_t ws_size,
                              hipStream_t stream) {
    const float* node = (const float*)d_in[0];   // [N,256]
    const float* agg  = (const float*)d_in[1];   // [N,256]
    const int*   nb   = (const int*)d_in[2];     // [N,32]
    const float* W    = (const float*)d_in[3];   // [512,256]
    const float* bias = (const float*)d_in[4];   // [256]

    float* out_attr = (float*)d_out;
    float* out_adj  = (float*)d_out + (size_t)NNODES * DIM;

    // workspace layout (all 16B-aligned)
    char* ws = (char*)d_ws;
    unsigned short* aggh  = (unsigned short*)(ws);
    unsigned short* aggl  = (unsigned short*)(ws + 5120000);
    unsigned short* nodeh = (unsigned short*)(ws + 10240000);
    unsigned short* nodel = (unsigned short*)(ws + 15360000);
    unsigned short* ctxh  = (unsigned short*)(ws + 20480000);
    unsigned short* ctxl  = (unsigned short*)(ws + 25600000);
    unsigned short* wth   = (unsigned short*)(ws + 30720000);
    unsigned short* wtl   = (unsigned short*)(ws + 31244288);

    const int count8 = NNODES * DIM / 8;         // 320000
    split_kernel<<<(count8 + 255) / 256, 256, 0, stream>>>(agg, aggh, aggl, count8);
    split_kernel<<<(count8 + 255) / 256, 256, 0, stream>>>(node, nodeh, nodel, count8);
    wt_split_kernel<<<256, 256, 0, stream>>>(W, wth, wtl);

    attn_ctx_kernel<<<NNODES, 256, 0, stream>>>(agg, nb, ctxh, ctxl);

    dim3 g2(2, NT);
    attr_mfma_kernel<<<g2, 256, 0, stream>>>(nodeh, nodel, ctxh, ctxl, wth, wtl, bias, out_attr);

    dim3 g3(NT, NT);
    adj_mfma_kernel<<<g3, 256, 0, stream>>>(aggh, aggl, out_adj);
}

// Round 6
// 247.189 us; speedup vs baseline: 5.5804x; 1.0337x over previous
//
#include <hip/hip_runtime.h>
#include <hip/hip_fp16.h>
#include <cstdint>
#include <cstddef>

#define NNODES 10000
#define DIM 256
#define MNB 32
#define NT 79   // ceil(10000/128)

typedef __attribute__((ext_vector_type(8))) _Float16 f16x8;
typedef __attribute__((ext_vector_type(4))) float f32x4;

// ---------------------------------------------------------------------------
// fp16 split helpers (RNE)
// ---------------------------------------------------------------------------
__device__ inline unsigned short f16_rne(float f) {
    return __half_as_ushort(__float2half(f));
}
__device__ inline float f16_to_f32(unsigned short h) {
    return __half2float(__ushort_as_half(h));
}

// ---------------------------------------------------------------------------
// Kernel 0: split f32 array into fp16 hi/lo arrays.
// ---------------------------------------------------------------------------
__global__ __launch_bounds__(256) void split_kernel(
    const float* __restrict__ in,
    unsigned short* __restrict__ hi,
    unsigned short* __restrict__ lo,
    int count8)
{
    const int i = blockIdx.x * 256 + threadIdx.x;      // 8 floats per thread
    if (i >= count8) return;
    float4 a = ((const float4*)in)[i * 2];
    float4 b = ((const float4*)in)[i * 2 + 1];
    float f[8] = {a.x, a.y, a.z, a.w, b.x, b.y, b.z, b.w};
    unsigned int hp[4], lp[4];
    #pragma unroll
    for (int j = 0; j < 4; ++j) {
        unsigned short h0 = f16_rne(f[2 * j]);
        unsigned short h1 = f16_rne(f[2 * j + 1]);
        unsigned short l0 = f16_rne(f[2 * j]     - f16_to_f32(h0));
        unsigned short l1 = f16_rne(f[2 * j + 1] - f16_to_f32(h1));
        hp[j] = (unsigned int)h0 | ((unsigned int)h1 << 16);
        lp[j] = (unsigned int)l0 | ((unsigned int)l1 << 16);
    }
    ((uint4*)hi)[i] = make_uint4(hp[0], hp[1], hp[2], hp[3]);
    ((uint4*)lo)[i] = make_uint4(lp[0], lp[1], lp[2], lp[3]);
}

// ---------------------------------------------------------------------------
// Kernel 0b: W [512,256] -> WT hi/lo [256,512] (transpose + split). Tiny.
// ---------------------------------------------------------------------------
__global__ __launch_bounds__(256) void wt_split_kernel(
    const float* __restrict__ W,
    unsigned short* __restrict__ wth,
    unsigned short* __restrict__ wtl)
{
    const int r = blockIdx.x;        // 0..255 : WT row = W col
    const int t = threadIdx.x;       // 0..255
    #pragma unroll
    for (int h = 0; h < 2; ++h) {
        const int k = h * 256 + t;   // 0..511
        float v = W[(size_t)k * DIM + r];
        unsigned short hh = f16_rne(v);
        unsigned short ll = f16_rne(v - f16_to_f32(hh));
        wth[(size_t)r * 512 + k] = hh;
        wtl[(size_t)r * 512 + k] = ll;
    }
}

// ---------------------------------------------------------------------------
// Kernel 1: attention context. One block per node. Neighbor rows staged in
// LDS (32KB) during the score pass and reused for the context pass.
// Emits ctx directly as fp16 hi/lo (consumed by the MFMA attr kernel).
// ---------------------------------------------------------------------------
__global__ __launch_bounds__(256) void attn_ctx_kernel(
    const float* __restrict__ agg,
    const int* __restrict__ nb_id,
    unsigned short* __restrict__ ctxh,
    unsigned short* __restrict__ ctxl)
{
    const int n = blockIdx.x;
    const int t = threadIdx.x;
    __shared__ float4 s_nb[MNB][64];   // 32 KB: gathered neighbor rows
    __shared__ float s_score[MNB];
    __shared__ int   s_idx[MNB];

    if (t < MNB) s_idx[t] = nb_id[n * MNB + t];
    __syncthreads();

    const int wave = t >> 6;
    const int lane = t & 63;

    const float4 q = ((const float4*)agg)[(size_t)n * 64 + lane];

    #pragma unroll
    for (int mi = 0; mi < 8; ++mi) {
        const int m = wave * 8 + mi;
        const int idx = s_idx[m];
        float4 v = make_float4(0.f, 0.f, 0.f, 0.f);
        if (idx >= 0) v = ((const float4*)agg)[(size_t)idx * 64 + lane];
        s_nb[m][lane] = v;
        float p = q.x * v.x + q.y * v.y + q.z * v.z + q.w * v.w;
        #pragma unroll
        for (int off = 32; off; off >>= 1) p += __shfl_down(p, off);
        if (lane == 0) s_score[m] = (idx >= 0) ? p * (1.f / 16.f) : -6.25e8f;
    }
    __syncthreads();

    float mx = -INFINITY;
    #pragma unroll
    for (int m = 0; m < MNB; ++m) mx = fmaxf(mx, s_score[m]);
    float w[MNB];
    float denom = 0.f;
    #pragma unroll
    for (int m = 0; m < MNB; ++m) { w[m] = __expf(s_score[m] - mx); denom += w[m]; }
    const float inv = 1.f / denom;

    const float* nbf = (const float*)s_nb;
    float c = 0.f;
    #pragma unroll
    for (int m = 0; m < MNB; ++m)
        c = fmaf(w[m] * inv, nbf[m * DIM + t], c);

    unsigned short h = f16_rne(c);
    unsigned short l = f16_rne(c - f16_to_f32(h));
    ctxh[(size_t)n * DIM + t] = h;
    ctxl[(size_t)n * DIM + t] = l;
}

// ---------------------------------------------------------------------------
// Shared LDS layout for both MFMA kernels
// ---------------------------------------------------------------------------
#define LDS_AH 0
#define LDS_AL 16384
#define LDS_BH 32768
#define LDS_BL 49152

// ---------------------------------------------------------------------------
// Kernel 2: decode_attribute = sigmoid([node|ctx] @ W + b) via fp16 split
// 2-pass MFMA (Ah*Bh + Ah*Bl; dropped Al*B term ~1.6e-4 on logits).
// ---------------------------------------------------------------------------
__global__ __launch_bounds__(256, 2) void attr_mfma_kernel(
    const unsigned short* __restrict__ nodeh,
    const unsigned short* __restrict__ nodel,
    const unsigned short* __restrict__ ctxh,
    const unsigned short* __restrict__ ctxl,
    const unsigned short* __restrict__ wth,
    const unsigned short* __restrict__ wtl,
    const float* __restrict__ bias,
    float* __restrict__ out)
{
    const int bj = blockIdx.x;        // 0..1   (output cols, 128 each)
    const int bi = blockIdx.y;        // 0..78  (output rows, 128 each)

    __shared__ __align__(16) char lds[65536];

    const int t = threadIdx.x;
    const int l = t & 63;
    const int w = t >> 6;
    const int wm = w >> 1;
    const int wn = w & 1;

    const int srow = t >> 1;          // 0..127
    const int shalf = t & 1;
    const int rowA = min(bi * 128 + srow, NNODES - 1);
    const size_t offA = (size_t)rowA * DIM;
    const int rowB = bj * 128 + srow;            // < 256 always
    const size_t offB = (size_t)rowB * 512;

    f32x4 acc[4][4] = {};

    for (int kb = 0; kb < 512; kb += 64) {
        const unsigned short* aH = (kb < 256) ? nodeh : ctxh;
        const unsigned short* aL = (kb < 256) ? nodel : ctxl;
        const int koff = kb & 255;
        __syncthreads();
        #pragma unroll
        for (int c = 0; c < 4; ++c) {
            const int k8 = shalf * 4 + c;                 // 16B chunk 0..7
            const int chp = k8 ^ (srow & 7);              // XOR swizzle
            uint4 vah = *(const uint4*)&aH[offA + koff + k8 * 8];
            uint4 val = *(const uint4*)&aL[offA + koff + k8 * 8];
            uint4 vbh = *(const uint4*)&wth[offB + kb + k8 * 8];
            uint4 vbl = *(const uint4*)&wtl[offB + kb + k8 * 8];
            *(uint4*)&lds[LDS_AH + srow * 128 + chp * 16] = vah;
            *(uint4*)&lds[LDS_AL + srow * 128 + chp * 16] = val;
            *(uint4*)&lds[LDS_BH + srow * 128 + chp * 16] = vbh;
            *(uint4*)&lds[LDS_BL + srow * 128 + chp * 16] = vbl;
        }
        __syncthreads();

        #pragma unroll
        for (int s = 0; s < 2; ++s) {
            f16x8 ah[4], bh[4], bl[4];
            #pragma unroll
            for (int m = 0; m < 4; ++m) {
                const int ra = wm * 64 + m * 16 + (l & 15);
                const int ca = (s * 4 + (l >> 4)) ^ (ra & 7);
                ah[m] = *(const f16x8*)&lds[LDS_AH + ra * 128 + ca * 16];
                const int rb = wn * 64 + m * 16 + (l & 15);
                const int cb = (s * 4 + (l >> 4)) ^ (rb & 7);
                bh[m] = *(const f16x8*)&lds[LDS_BH + rb * 128 + cb * 16];
                bl[m] = *(const f16x8*)&lds[LDS_BL + rb * 128 + cb * 16];
            }
            #pragma unroll
            for (int m = 0; m < 4; ++m)
                #pragma unroll
                for (int n = 0; n < 4; ++n) {
                    acc[m][n] = __builtin_amdgcn_mfma_f32_16x16x32_f16(ah[m], bh[n], acc[m][n], 0, 0, 0);
                    acc[m][n] = __builtin_amdgcn_mfma_f32_16x16x32_f16(ah[m], bl[n], acc[m][n], 0, 0, 0);
                }
        }
    }

    // bias + sigmoid
    float bias_v[4];
    #pragma unroll
    for (int n = 0; n < 4; ++n)
        bias_v[n] = bias[bj * 128 + wn * 64 + n * 16 + (l & 15)];
    #pragma unroll
    for (int m = 0; m < 4; ++m)
        #pragma unroll
        for (int n = 0; n < 4; ++n)
            #pragma unroll
            for (int j = 0; j < 4; ++j)
                acc[m][n][j] = 1.f / (1.f + __expf(-(acc[m][n][j] + bias_v[n])));

    float* sf = (float*)lds;
    __syncthreads();
    #pragma unroll
    for (int m = 0; m < 4; ++m)
        #pragma unroll
        for (int n = 0; n < 4; ++n)
            #pragma unroll
            for (int j = 0; j < 4; ++j) {
                const int r = wm * 64 + m * 16 + (l >> 4) * 4 + j;
                const int c = wn * 64 + n * 16 + (l & 15);
                sf[r * 128 + c] = acc[m][n][j];
            }
    __syncthreads();
    {
        const int c4 = t & 31;
        const int gc = bj * 128 + c4 * 4;       // < 256 always
        #pragma unroll
        for (int it = 0; it < 16; ++it) {
            const int r = it * 8 + (t >> 5);
            const int gr = bi * 128 + r;
            if (gr < NNODES) {
                float4 v = *(float4*)&sf[r * 128 + c4 * 4];
                *(float4*)&out[(size_t)gr * DIM + gc] = v;
            }
        }
    }
}

// ---------------------------------------------------------------------------
// Kernel 3: decode_adj = sigmoid(agg @ agg^T) via fp16 split 2-pass MFMA.
// 128x128 tile, 2x2 waves. Upper triangle only; both orientations written
// through LDS as contiguous 512B row segments.
// ---------------------------------------------------------------------------
__global__ __launch_bounds__(256, 2) void adj_mfma_kernel(
    const unsigned short* __restrict__ aggh,
    const unsigned short* __restrict__ aggl,
    float* __restrict__ out)
{
    const int bj = blockIdx.x;
    const int bi = blockIdx.y;
    if (bi > bj) return;

    __shared__ __align__(16) char lds[65536];

    const int t = threadIdx.x;
    const int l = t & 63;
    const int w = t >> 6;
    const int wm = w >> 1;
    const int wn = w & 1;

    const int srow = t >> 1;
    const int shalf = t & 1;
    const int rowA = min(bi * 128 + srow, NNODES - 1);
    const int rowB = min(bj * 128 + srow, NNODES - 1);
    const size_t offA = (size_t)rowA * DIM;
    const size_t offB = (size_t)rowB * DIM;

    f32x4 acc[4][4] = {};

    for (int kb = 0; kb < DIM; kb += 64) {
        __syncthreads();
        #pragma unroll
        for (int c = 0; c < 4; ++c) {
            const int k8 = shalf * 4 + c;
            const int chp = k8 ^ (srow & 7);
            uint4 vah = *(const uint4*)&aggh[offA + kb + k8 * 8];
            uint4 val = *(const uint4*)&aggl[offA + kb + k8 * 8];
            uint4 vbh = *(const uint4*)&aggh[offB + kb + k8 * 8];
            uint4 vbl = *(const uint4*)&aggl[offB + kb + k8 * 8];
            *(uint4*)&lds[LDS_AH + srow * 128 + chp * 16] = vah;
            *(uint4*)&lds[LDS_AL + srow * 128 + chp * 16] = val;
            *(uint4*)&lds[LDS_BH + srow * 128 + chp * 16] = vbh;
            *(uint4*)&lds[LDS_BL + srow * 128 + chp * 16] = vbl;
        }
        __syncthreads();

        #pragma unroll
        for (int s = 0; s < 2; ++s) {
            f16x8 ah[4], bh[4], bl[4];
            #pragma unroll
            for (int m = 0; m < 4; ++m) {
                const int ra = wm * 64 + m * 16 + (l & 15);
                const int ca = (s * 4 + (l >> 4)) ^ (ra & 7);
                ah[m] = *(const f16x8*)&lds[LDS_AH + ra * 128 + ca * 16];
                const int rb = wn * 64 + m * 16 + (l & 15);
                const int cb = (s * 4 + (l >> 4)) ^ (rb & 7);
                bh[m] = *(const f16x8*)&lds[LDS_BH + rb * 128 + cb * 16];
                bl[m] = *(const f16x8*)&lds[LDS_BL + rb * 128 + cb * 16];
            }
            #pragma unroll
            for (int m = 0; m < 4; ++m)
                #pragma unroll
                for (int n = 0; n < 4; ++n) {
                    acc[m][n] = __builtin_amdgcn_mfma_f32_16x16x32_f16(ah[m], bh[n], acc[m][n], 0, 0, 0);
                    acc[m][n] = __builtin_amdgcn_mfma_f32_16x16x32_f16(ah[m], bl[n], acc[m][n], 0, 0, 0);
                }
        }
    }

    #pragma unroll
    for (int m = 0; m < 4; ++m)
        #pragma unroll
        for (int n = 0; n < 4; ++n)
            #pragma unroll
            for (int j = 0; j < 4; ++j)
                acc[m][n][j] = 1.f / (1.f + __expf(-acc[m][n][j]));

    float* sf = (float*)lds;

    __syncthreads();
    #pragma unroll
    for (int m = 0; m < 4; ++m)
        #pragma unroll
        for (int n = 0; n < 4; ++n)
            #pragma unroll
            for (int j = 0; j < 4; ++j) {
                const int r = wm * 64 + m * 16 + (l >> 4) * 4 + j;
                const int c = wn * 64 + n * 16 + (l & 15);
                sf[r * 128 + c] = acc[m][n][j];
            }
    __syncthreads();
    {
        const int c4 = t & 31;
        const int gc = bj * 128 + c4 * 4;
        #pragma unroll
        for (int it = 0; it < 16; ++it) {
            const int r = it * 8 + (t >> 5);
            const int gr = bi * 128 + r;
            if (gr < NNODES && gc < NNODES) {
                f32x4 v = *(f32x4*)&sf[r * 128 + c4 * 4];
                __builtin_nontemporal_store(v, (f32x4*)&out[(size_t)gr * NNODES + gc]);
            }
        }
    }

    if (bi != bj) {
        __syncthreads();
        #pragma unroll
        for (int m = 0; m < 4; ++m)
            #pragma unroll
            for (int n = 0; n < 4; ++n)
                #pragma unroll
                for (int j = 0; j < 4; ++j) {
                    const int r = wm * 64 + m * 16 + (l >> 4) * 4 + j;
                    const int c = wn * 64 + n * 16 + (l & 15);
                    sf[c * 128 + (((r >> 2) ^ (c & 7)) << 2) + (r & 3)] = acc[m][n][j];
                }
        __syncthreads();
        {
            const int g = t & 31;
            const int gc2 = bi * 128 + g * 4;
            #pragma unroll
            for (int it = 0; it < 16; ++it) {
                const int rt = it * 8 + (t >> 5);
                const int gr2 = bj * 128 + rt;
                if (gr2 < NNODES) {
                    f32x4 v = *(f32x4*)&sf[rt * 128 + ((g ^ (rt & 7)) << 2)];
                    __builtin_nontemporal_store(v, (f32x4*)&out[(size_t)gr2 * NNODES + gc2]);
                }
            }
        }
    }
}

extern "C" void kernel_launch(void* const* d_in, const int* in_sizes, int n_in,
                              void* d_out, int out_size, void* d_ws, size_t ws_size,
                              hipStream_t stream) {
    const float* node = (const float*)d_in[0];   // [N,256]
    const float* agg  = (const float*)d_in[1];   // [N,256]
    const int*   nb   = (const int*)d_in[2];     // [N,32]
    const float* W    = (const float*)d_in[3];   // [512,256]
    const float* bias = (const float*)d_in[4];   // [256]

    float* out_attr = (float*)d_out;
    float* out_adj  = (float*)d_out + (size_t)NNODES * DIM;

    // workspace layout (all 16B-aligned)
    char* ws = (char*)d_ws;
    unsigned short* aggh  = (unsigned short*)(ws);
    unsigned short* aggl  = (unsigned short*)(ws + 5120000);
    unsigned short* nodeh = (unsigned short*)(ws + 10240000);
    unsigned short* nodel = (unsigned short*)(ws + 15360000);
    unsigned short* ctxh  = (unsigned short*)(ws + 20480000);
    unsigned short* ctxl  = (unsigned short*)(ws + 25600000);
    unsigned short* wth   = (unsigned short*)(ws + 30720000);
    unsigned short* wtl   = (unsigned short*)(ws + 31244288);

    const int count8 = NNODES * DIM / 8;         // 320000
    split_kernel<<<(count8 + 255) / 256, 256, 0, stream>>>(agg, aggh, aggl, count8);
    split_kernel<<<(count8 + 255) / 256, 256, 0, stream>>>(node, nodeh, nodel, count8);
    wt_split_kernel<<<256, 256, 0, stream>>>(W, wth, wtl);

    attn_ctx_kernel<<<NNODES, 256, 0, stream>>>(agg, nb, ctxh, ctxl);

    dim3 g2(2, NT);
    attr_mfma_kernel<<<g2, 256, 0, stream>>>(nodeh, nodel, ctxh, ctxl, wth, wtl, bias, out_attr);

    dim3 g3(NT, NT);
    adj_mfma_kernel<<<g3, 256, 0, stream>>>(aggh, aggl, out_adj);
}

// Round 7
// 211.529 us; speedup vs baseline: 6.5212x; 1.1686x over previous
//
#include <hip/hip_runtime.h>
#include <hip/hip_fp16.h>
#include <cstdint>
#include <cstddef>

#define NNODES 10000
#define DIM 256
#define MNB 32
#define NT 79            // ceil(10000/128)
#define NTRI (NT*(NT+1)/2)   // 3160 upper-triangle tiles

typedef __attribute__((ext_vector_type(8))) _Float16 f16x8;
typedef __attribute__((ext_vector_type(4))) float f32x4;

__device__ inline unsigned short f16_rne(float f) {
    return __half_as_ushort(__float2half(f));
}
__device__ inline float f16_to_f32(unsigned short h) {
    return __half2float(__ushort_as_half(h));
}

// ---------------------------------------------------------------------------
// Kernel 0: split f32 array into fp16 hi/lo arrays.
// ---------------------------------------------------------------------------
__global__ __launch_bounds__(256) void split_kernel(
    const float* __restrict__ in,
    unsigned short* __restrict__ hi,
    unsigned short* __restrict__ lo,
    int count8)
{
    const int i = blockIdx.x * 256 + threadIdx.x;
    if (i >= count8) return;
    float4 a = ((const float4*)in)[i * 2];
    float4 b = ((const float4*)in)[i * 2 + 1];
    float f[8] = {a.x, a.y, a.z, a.w, b.x, b.y, b.z, b.w};
    unsigned int hp[4], lp[4];
    #pragma unroll
    for (int j = 0; j < 4; ++j) {
        unsigned short h0 = f16_rne(f[2 * j]);
        unsigned short h1 = f16_rne(f[2 * j + 1]);
        unsigned short l0 = f16_rne(f[2 * j]     - f16_to_f32(h0));
        unsigned short l1 = f16_rne(f[2 * j + 1] - f16_to_f32(h1));
        hp[j] = (unsigned int)h0 | ((unsigned int)h1 << 16);
        lp[j] = (unsigned int)l0 | ((unsigned int)l1 << 16);
    }
    ((uint4*)hi)[i] = make_uint4(hp[0], hp[1], hp[2], hp[3]);
    ((uint4*)lo)[i] = make_uint4(lp[0], lp[1], lp[2], lp[3]);
}

// ---------------------------------------------------------------------------
// Kernel 0b: W [512,256] -> WT hi/lo [256,512] (transpose + split).
// ---------------------------------------------------------------------------
__global__ __launch_bounds__(256) void wt_split_kernel(
    const float* __restrict__ W,
    unsigned short* __restrict__ wth,
    unsigned short* __restrict__ wtl)
{
    const int r = blockIdx.x;
    const int t = threadIdx.x;
    #pragma unroll
    for (int h = 0; h < 2; ++h) {
        const int k = h * 256 + t;
        float v = W[(size_t)k * DIM + r];
        unsigned short hh = f16_rne(v);
        unsigned short ll = f16_rne(v - f16_to_f32(hh));
        wth[(size_t)r * 512 + k] = hh;
        wtl[(size_t)r * 512 + k] = ll;
    }
}

// ---------------------------------------------------------------------------
// Kernel 1: attention context (LDS-staged neighbor rows), emits fp16 hi.
// ---------------------------------------------------------------------------
__global__ __launch_bounds__(256) void attn_ctx_kernel(
    const float* __restrict__ agg,
    const int* __restrict__ nb_id,
    unsigned short* __restrict__ ctxh)
{
    const int n = blockIdx.x;
    const int t = threadIdx.x;
    __shared__ float4 s_nb[MNB][64];
    __shared__ float s_score[MNB];
    __shared__ int   s_idx[MNB];

    if (t < MNB) s_idx[t] = nb_id[n * MNB + t];
    __syncthreads();

    const int wave = t >> 6;
    const int lane = t & 63;
    const float4 q = ((const float4*)agg)[(size_t)n * 64 + lane];

    #pragma unroll
    for (int mi = 0; mi < 8; ++mi) {
        const int m = wave * 8 + mi;
        const int idx = s_idx[m];
        float4 v = make_float4(0.f, 0.f, 0.f, 0.f);
        if (idx >= 0) v = ((const float4*)agg)[(size_t)idx * 64 + lane];
        s_nb[m][lane] = v;
        float p = q.x * v.x + q.y * v.y + q.z * v.z + q.w * v.w;
        #pragma unroll
        for (int off = 32; off; off >>= 1) p += __shfl_down(p, off);
        if (lane == 0) s_score[m] = (idx >= 0) ? p * (1.f / 16.f) : -6.25e8f;
    }
    __syncthreads();

    float mx = -INFINITY;
    #pragma unroll
    for (int m = 0; m < MNB; ++m) mx = fmaxf(mx, s_score[m]);
    float w[MNB];
    float denom = 0.f;
    #pragma unroll
    for (int m = 0; m < MNB; ++m) { w[m] = __expf(s_score[m] - mx); denom += w[m]; }
    const float inv = 1.f / denom;

    const float* nbf = (const float*)s_nb;
    float c = 0.f;
    #pragma unroll
    for (int m = 0; m < MNB; ++m)
        c = fmaf(w[m] * inv, nbf[m * DIM + t], c);

    ctxh[(size_t)n * DIM + t] = f16_rne(c);
}

// ---------------------------------------------------------------------------
// LDS layout: 3 staged arrays (AH, BH, BL), 16 KB each = 48 KB total.
// Repack reuses bytes 0..32767 as a 64x128 f32 half-tile.
// ---------------------------------------------------------------------------
#define LDS_AH 0
#define LDS_BH 16384
#define LDS_BL 32768

// ---------------------------------------------------------------------------
// Kernel 2: decode_attribute = sigmoid([node|ctx] @ W + b), fp16 2-pass MFMA.
// A-lo never staged (unused). 48 KB LDS, 3 blocks/CU.
// ---------------------------------------------------------------------------
__global__ __launch_bounds__(256, 3) void attr_mfma_kernel(
    const unsigned short* __restrict__ nodeh,
    const unsigned short* __restrict__ ctxh,
    const unsigned short* __restrict__ wth,
    const unsigned short* __restrict__ wtl,
    const float* __restrict__ bias,
    float* __restrict__ out)
{
    const int bj = blockIdx.x;        // 0..1
    const int bi = blockIdx.y;        // 0..78

    __shared__ __align__(16) char lds[49152];

    const int t = threadIdx.x;
    const int l = t & 63;
    const int w = t >> 6;
    const int wm = w >> 1;
    const int wn = w & 1;

    const int srow = t >> 1;
    const int shalf = t & 1;
    const int rowA = min(bi * 128 + srow, NNODES - 1);
    const size_t offA = (size_t)rowA * DIM;
    const int rowB = bj * 128 + srow;
    const size_t offB = (size_t)rowB * 512;

    f32x4 acc[4][4] = {};

    for (int kb = 0; kb < 512; kb += 64) {
        const unsigned short* aH = (kb < 256) ? nodeh : ctxh;
        const int koff = kb & 255;
        __syncthreads();
        #pragma unroll
        for (int c = 0; c < 4; ++c) {
            const int k8 = shalf * 4 + c;
            const int chp = k8 ^ (srow & 7);
            uint4 vah = *(const uint4*)&aH[offA + koff + k8 * 8];
            uint4 vbh = *(const uint4*)&wth[offB + kb + k8 * 8];
            uint4 vbl = *(const uint4*)&wtl[offB + kb + k8 * 8];
            *(uint4*)&lds[LDS_AH + srow * 128 + chp * 16] = vah;
            *(uint4*)&lds[LDS_BH + srow * 128 + chp * 16] = vbh;
            *(uint4*)&lds[LDS_BL + srow * 128 + chp * 16] = vbl;
        }
        __syncthreads();

        #pragma unroll
        for (int s = 0; s < 2; ++s) {
            f16x8 ah[4], bh[4], bl[4];
            #pragma unroll
            for (int m = 0; m < 4; ++m) {
                const int ra = wm * 64 + m * 16 + (l & 15);
                const int ca = (s * 4 + (l >> 4)) ^ (ra & 7);
                ah[m] = *(const f16x8*)&lds[LDS_AH + ra * 128 + ca * 16];
                const int rb = wn * 64 + m * 16 + (l & 15);
                const int cb = (s * 4 + (l >> 4)) ^ (rb & 7);
                bh[m] = *(const f16x8*)&lds[LDS_BH + rb * 128 + cb * 16];
                bl[m] = *(const f16x8*)&lds[LDS_BL + rb * 128 + cb * 16];
            }
            #pragma unroll
            for (int m = 0; m < 4; ++m)
                #pragma unroll
                for (int n = 0; n < 4; ++n) {
                    acc[m][n] = __builtin_amdgcn_mfma_f32_16x16x32_f16(ah[m], bh[n], acc[m][n], 0, 0, 0);
                    acc[m][n] = __builtin_amdgcn_mfma_f32_16x16x32_f16(ah[m], bl[n], acc[m][n], 0, 0, 0);
                }
        }
    }

    float bias_v[4];
    #pragma unroll
    for (int n = 0; n < 4; ++n)
        bias_v[n] = bias[bj * 128 + wn * 64 + n * 16 + (l & 15)];
    #pragma unroll
    for (int m = 0; m < 4; ++m)
        #pragma unroll
        for (int n = 0; n < 4; ++n)
            #pragma unroll
            for (int j = 0; j < 4; ++j)
                acc[m][n][j] = 1.f / (1.f + __expf(-(acc[m][n][j] + bias_v[n])));

    // half-tile repack (32 KB), rows 0-63 then 64-127
    float* sf = (float*)lds;
    #pragma unroll
    for (int half = 0; half < 2; ++half) {
        __syncthreads();
        if (wm == half) {
            #pragma unroll
            for (int m = 0; m < 4; ++m)
                #pragma unroll
                for (int n = 0; n < 4; ++n)
                    #pragma unroll
                    for (int j = 0; j < 4; ++j) {
                        const int r = m * 16 + (l >> 4) * 4 + j;   // 0..63
                        const int c = wn * 64 + n * 16 + (l & 15);
                        sf[r * 128 + c] = acc[m][n][j];
                    }
        }
        __syncthreads();
        const int c4 = t & 31;
        const int gc = bj * 128 + c4 * 4;
        #pragma unroll
        for (int it = 0; it < 8; ++it) {
            const int r = it * 8 + (t >> 5);
            const int gr = bi * 128 + half * 64 + r;
            if (gr < NNODES) {
                float4 v = *(float4*)&sf[r * 128 + c4 * 4];
                *(float4*)&out[(size_t)gr * DIM + gc] = v;
            }
        }
    }
}

// ---------------------------------------------------------------------------
// Kernel 3: decode_adj = sigmoid(agg @ agg^T), fp16 2-pass MFMA.
// Linearized upper-triangle grid (3160 blocks). 48 KB LDS, 3 blocks/CU.
// Half-tile (32 KB) repack for both orientations.
// ---------------------------------------------------------------------------
__global__ __launch_bounds__(256, 3) void adj_mfma_kernel(
    const unsigned short* __restrict__ aggh,
    const unsigned short* __restrict__ aggl,
    float* __restrict__ out)
{
    // map linear tile id -> (bi, bj) with bj >= bi
    int tid = blockIdx.x;
    int bi = (int)((2 * NT + 1 - sqrtf((float)((2 * NT + 1) * (2 * NT + 1)) - 8.0f * (float)tid)) * 0.5f);
    // row start s(b) = b*NT - b*(b-1)/2 ; fixup for float error
    #pragma unroll 4
    while (bi > 0 && bi * NT - bi * (bi - 1) / 2 > tid) --bi;
    #pragma unroll 4
    while ((bi + 1) * NT - (bi + 1) * bi / 2 <= tid) ++bi;
    const int bj = bi + (tid - (bi * NT - bi * (bi - 1) / 2));

    __shared__ __align__(16) char lds[49152];

    const int t = threadIdx.x;
    const int l = t & 63;
    const int w = t >> 6;
    const int wm = w >> 1;
    const int wn = w & 1;

    const int srow = t >> 1;
    const int shalf = t & 1;
    const int rowA = min(bi * 128 + srow, NNODES - 1);
    const int rowB = min(bj * 128 + srow, NNODES - 1);
    const size_t offA = (size_t)rowA * DIM;
    const size_t offB = (size_t)rowB * DIM;

    f32x4 acc[4][4] = {};

    for (int kb = 0; kb < DIM; kb += 64) {
        __syncthreads();
        #pragma unroll
        for (int c = 0; c < 4; ++c) {
            const int k8 = shalf * 4 + c;
            const int chp = k8 ^ (srow & 7);
            uint4 vah = *(const uint4*)&aggh[offA + kb + k8 * 8];
            uint4 vbh = *(const uint4*)&aggh[offB + kb + k8 * 8];
            uint4 vbl = *(const uint4*)&aggl[offB + kb + k8 * 8];
            *(uint4*)&lds[LDS_AH + srow * 128 + chp * 16] = vah;
            *(uint4*)&lds[LDS_BH + srow * 128 + chp * 16] = vbh;
            *(uint4*)&lds[LDS_BL + srow * 128 + chp * 16] = vbl;
        }
        __syncthreads();

        #pragma unroll
        for (int s = 0; s < 2; ++s) {
            f16x8 ah[4], bh[4], bl[4];
            #pragma unroll
            for (int m = 0; m < 4; ++m) {
                const int ra = wm * 64 + m * 16 + (l & 15);
                const int ca = (s * 4 + (l >> 4)) ^ (ra & 7);
                ah[m] = *(const f16x8*)&lds[LDS_AH + ra * 128 + ca * 16];
                const int rb = wn * 64 + m * 16 + (l & 15);
                const int cb = (s * 4 + (l >> 4)) ^ (rb & 7);
                bh[m] = *(const f16x8*)&lds[LDS_BH + rb * 128 + cb * 16];
                bl[m] = *(const f16x8*)&lds[LDS_BL + rb * 128 + cb * 16];
            }
            #pragma unroll
            for (int m = 0; m < 4; ++m)
                #pragma unroll
                for (int n = 0; n < 4; ++n) {
                    acc[m][n] = __builtin_amdgcn_mfma_f32_16x16x32_f16(ah[m], bh[n], acc[m][n], 0, 0, 0);
                    acc[m][n] = __builtin_amdgcn_mfma_f32_16x16x32_f16(ah[m], bl[n], acc[m][n], 0, 0, 0);
                }
        }
    }

    #pragma unroll
    for (int m = 0; m < 4; ++m)
        #pragma unroll
        for (int n = 0; n < 4; ++n)
            #pragma unroll
            for (int j = 0; j < 4; ++j)
                acc[m][n][j] = 1.f / (1.f + __expf(-acc[m][n][j]));

    float* sf = (float*)lds;
    const size_t NN = NNODES;

    // ---- pass 1: normal orientation, two 64-row halves
    #pragma unroll
    for (int half = 0; half < 2; ++half) {
        __syncthreads();
        if (wm == half) {
            #pragma unroll
            for (int m = 0; m < 4; ++m)
                #pragma unroll
                for (int n = 0; n < 4; ++n)
                    #pragma unroll
                    for (int j = 0; j < 4; ++j) {
                        const int r = m * 16 + (l >> 4) * 4 + j;   // 0..63
                        const int c = wn * 64 + n * 16 + (l & 15);
                        sf[r * 128 + c] = acc[m][n][j];
                    }
        }
        __syncthreads();
        const int c4 = t & 31;
        const int gc = bj * 128 + c4 * 4;
        #pragma unroll
        for (int it = 0; it < 8; ++it) {
            const int r = it * 8 + (t >> 5);
            const int gr = bi * 128 + half * 64 + r;
            if (gr < NNODES && gc < NNODES) {
                f32x4 v = *(f32x4*)&sf[r * 128 + c4 * 4];
                __builtin_nontemporal_store(v, (f32x4*)&out[(size_t)gr * NN + gc]);
            }
        }
    }

    // ---- pass 2: transposed image for the mirror tile (skip on diagonal)
    if (bi != bj) {
        #pragma unroll
        for (int half = 0; half < 2; ++half) {
            __syncthreads();
            if (wn == half) {
                #pragma unroll
                for (int m = 0; m < 4; ++m)
                    #pragma unroll
                    for (int n = 0; n < 4; ++n)
                        #pragma unroll
                        for (int j = 0; j < 4; ++j) {
                            const int r = wm * 64 + m * 16 + (l >> 4) * 4 + j;
                            const int c = n * 16 + (l & 15);       // 0..63
                            sf[c * 128 + (((r >> 2) ^ (c & 7)) << 2) + (r & 3)] = acc[m][n][j];
                        }
            }
            __syncthreads();
            const int g = t & 31;
            const int gc2 = bi * 128 + g * 4;       // bi <= 77 -> in range
            #pragma unroll
            for (int it = 0; it < 8; ++it) {
                const int rt = it * 8 + (t >> 5);   // 0..63 within half
                const int gr2 = bj * 128 + half * 64 + rt;
                if (gr2 < NNODES) {
                    f32x4 v = *(f32x4*)&sf[rt * 128 + ((g ^ (rt & 7)) << 2)];
                    __builtin_nontemporal_store(v, (f32x4*)&out[(size_t)gr2 * NN + gc2]);
                }
            }
        }
    }
}

extern "C" void kernel_launch(void* const* d_in, const int* in_sizes, int n_in,
                              void* d_out, int out_size, void* d_ws, size_t ws_size,
                              hipStream_t stream) {
    const float* node = (const float*)d_in[0];
    const float* agg  = (const float*)d_in[1];
    const int*   nb   = (const int*)d_in[2];
    const float* W    = (const float*)d_in[3];
    const float* bias = (const float*)d_in[4];

    float* out_attr = (float*)d_out;
    float* out_adj  = (float*)d_out + (size_t)NNODES * DIM;

    char* ws = (char*)d_ws;
    unsigned short* aggh  = (unsigned short*)(ws);
    unsigned short* aggl  = (unsigned short*)(ws + 5120000);
    unsigned short* nodeh = (unsigned short*)(ws + 10240000);
    unsigned short* nodel = (unsigned short*)(ws + 15360000);  // written, unused
    unsigned short* ctxh  = (unsigned short*)(ws + 20480000);
    unsigned short* wth   = (unsigned short*)(ws + 25600000);
    unsigned short* wtl   = (unsigned short*)(ws + 26124288);

    const int count8 = NNODES * DIM / 8;
    split_kernel<<<(count8 + 255) / 256, 256, 0, stream>>>(agg, aggh, aggl, count8);

    adj_mfma_kernel<<<NTRI, 256, 0, stream>>>(aggh, aggl, out_adj);

    split_kernel<<<(count8 + 255) / 256, 256, 0, stream>>>(node, nodeh, nodel, count8);
    wt_split_kernel<<<256, 256, 0, stream>>>(W, wth, wtl);
    attn_ctx_kernel<<<NNODES, 256, 0, stream>>>(agg, nb, ctxh);

    dim3 g2(2, NT);
    attr_mfma_kernel<<<g2, 256, 0, stream>>>(nodeh, ctxh, wth, wtl, bias, out_attr);
}